// Round 18
// baseline (535.039 us; speedup 1.0000x reference)
//
#include <hip/hip_runtime.h>
#include <hip/hip_bf16.h>

// RQ-VAE residual quantization, MI355X gfx950 — fused 4-level scoring.
// data [65536][256] f32, codebooks [4][1024][256] f32.
// out = [zq_stack 4*65536*256][semantic_ids 65536*4 (as float)][loss 1], all f32.
//
// k_score4: ONE persistent dispatch runs all 4 levels (row-local problem,
// no cross-block dependency). BM=256 rows, 1024 threads = 16 waves x 16
// rows, ONE block per CU (grid 256), 128-code chunks in a 2x64KB LDS
// double buffer -> 8 barriers/level. Fusion wins vs r17: (1) no
// inter-level full-device drains; (2) r' written by a block is re-read by
// the SAME block next level (L2-hot, ~8MB/XCD footprint); (3) chunk 0 of
// the next level is DMA-issued during refine+epilogue of the current one.
// Wave code unchanged: single-pass scores, candidates vs post-chunk
// running-min + MARGIN; true argmin ALWAYS collected (bf16 error bound
// 2*3.45 < 8) so cnt==1 rows take their sole candidate (exact); cnt>1 ->
// wave-cooperative coalesced fp64 rescore (exact, lowest-index tie-break);
// cnt==0 or >CAP -> full scan. Epilogue writes winner ints + r' = r - q.
// Same-block global RAW via __threadfence_block + __syncthreads.
// k_final recomputes the exact fp32 reference chain from data + codes.
// Residual scratch = zq_stack[3] slot of d_out (read-before-write).
// NOTE: WRITE_SIZE ~197 MB is legit (3 levels' r' + ids), not spills.

#define NROWS   65536
#define DIM     256
#define KCODES  1024
#define LEVELS  4
#define CH      (NROWS * DIM)
#define IDS_OFF (LEVELS * CH)

#define BM      256
#define NCHUNK  8
#define CAP     32
#define MARGIN  8.0f
#define CHUNK_USH 32768          // 128 codes * 256 bf16 = 64 KB
#define LVL_USH 262144           // 1024 * 256

typedef __attribute__((ext_vector_type(8))) short bf16x8;
typedef __attribute__((ext_vector_type(4))) float f32x4;
typedef const __attribute__((address_space(1))) void* gp_t;
typedef __attribute__((address_space(3))) void* lp_t;

__device__ __forceinline__ unsigned short f2bf(float x) {
    __hip_bfloat16 h = __float2bfloat16(x);
    unsigned short r; __builtin_memcpy(&r, &h, 2); return r;
}
__device__ __forceinline__ float bf2f(unsigned short u) {
    __hip_bfloat16 h; __builtin_memcpy(&h, &u, 2); return __bfloat162float(h);
}

// ---- k_prep: frag-tiled bf16 codebook + fp32 sum(c_bf16^2) + fp64 sum(c^2) ----
// Layout (ushort idx): ((((L*16+chunk64)*4+nt)*8+kk)*64 + (g*16+li))*8 + h
// Fully contiguous in code order: any aligned 64 KB window holds 128
// consecutive codes (codes t*128..t*128+127 live at cbwL + t*CHUNK_USH).
__global__ __launch_bounds__(64) void k_prep(const float* __restrict__ cb,
                                             unsigned short* __restrict__ cbw,
                                             float* __restrict__ cn2w,
                                             double* __restrict__ cn2d) {
    int cr = blockIdx.x;                 // level*1024 + code
    int L = cr >> 10, c = cr & 1023;
    int l = threadIdx.x;                 // handles floats l*4..l*4+3
    float4 v = *(const float4*)(cb + (size_t)cr * DIM + l * 4);
    ushort4 st;
    st.x = f2bf(v.x); st.y = f2bf(v.y); st.z = f2bf(v.z); st.w = f2bf(v.w);
    int b = l * 8;
    int kk = b >> 6, g = (b >> 4) & 3, h = (b & 15) >> 1;
    int idx = ((((L * 16 + (c >> 6)) * 4 + ((c >> 4) & 3)) * 8 + kk) * 64
               + (g * 16 + (c & 15))) * 8 + h;
    *(ushort4*)(cbw + idx) = st;
    float f0 = bf2f(st.x), f1 = bf2f(st.y), f2 = bf2f(st.z), f3 = bf2f(st.w);
    float sq = f0 * f0 + f1 * f1 + f2 * f2 + f3 * f3;
    double dq = (double)v.x * v.x + (double)v.y * v.y
              + (double)v.z * v.z + (double)v.w * v.w;
    #pragma unroll
    for (int m = 32; m; m >>= 1) {
        sq += __shfl_xor(sq, m);
        dq += __shfl_xor(dq, m);
    }
    if (l == 0) { cn2w[cr] = sq; cn2d[cr] = dq; }
}

// ---- k_score4: all 4 levels fused; per level: 16-wave single-pass scores
//      + cnt==1 skip + coalesced refine + residual epilogue ----
__global__ __launch_bounds__(1024) void k_score4(
    const float* __restrict__ data,
    const float* __restrict__ cbf0,           // [4][1024][256] f32
    const unsigned short* __restrict__ cbw0,  // frag-tiled bf16, all levels
    const float* __restrict__ cn2w,           // [4][1024]
    const double* __restrict__ cn2d,          // [4][1024]
    int* __restrict__ wid_out,                // [N][4] ints (ids slot)
    float* __restrict__ rscr)                 // residual scratch [N][256]
{
    __shared__ unsigned short cbuf[2 * CHUNK_USH];   // 128 KB double buffer
    __shared__ unsigned short cand[BM * CAP];        // 16 KB
    __shared__ int cnt[BM];
    __shared__ int winid[BM];

    const int tid = threadIdx.x;
    const int w = tid >> 6, l = tid & 63;
    const int g = l >> 4, li = l & 15;
    const int rows0 = blockIdx.x * BM;

    // stage 128-code chunk T of level-base B into buffer T&1
    #define STAGE(B, T) do {                                                   \
        const unsigned short* _g = (B) + (T) * CHUNK_USH;                      \
        unsigned short* _d = &cbuf[((T) & 1) * CHUNK_USH];                     \
        _Pragma("unroll")                                                      \
        for (int _r = 0; _r < 4; ++_r)                                         \
            __builtin_amdgcn_global_load_lds((gp_t)(_g + _r * 8192 + tid * 8), \
                                             (lp_t)(_d + _r * 8192 + tid * 8), \
                                             16, 0, 0);                        \
    } while (0)

    STAGE(cbw0, 0);                      // level 0 chunk 0, issued early

    for (int lv = 0; lv < LEVELS; ++lv) {
        const float* rsrc = lv ? (const float*)rscr : data;
        const float* cbf  = cbf0 + (size_t)lv * KCODES * DIM;
        const unsigned short* cbwL = cbw0 + (size_t)lv * LVL_USH;
        const float*  cn2L  = cn2w + (size_t)lv * KCODES;
        const double* cn2dL = cn2d + (size_t)lv * KCODES;
        float* rnext = (lv < 3) ? rscr : nullptr;

        if (tid < BM) cnt[tid] = 0;

        // A-fragments: 16 rows per wave (L2-hot for lv>0: same block wrote r')
        bf16x8 af[8];
        {
            int row = rows0 + w * 16 + li;
            const float* rp = rsrc + (size_t)row * DIM;
            #pragma unroll
            for (int kk = 0; kk < 8; ++kk) {
                int d0 = kk * 32 + 8 * g;
                float4 v0 = *(const float4*)(rp + d0);
                float4 v1 = *(const float4*)(rp + d0 + 4);
                bf16x8 t;
                t[0] = (short)f2bf(v0.x); t[1] = (short)f2bf(v0.y);
                t[2] = (short)f2bf(v0.z); t[3] = (short)f2bf(v0.w);
                t[4] = (short)f2bf(v1.x); t[5] = (short)f2bf(v1.y);
                t[6] = (short)f2bf(v1.z); t[7] = (short)f2bf(v1.w);
                af[kk] = t;
            }
        }

        float minv[4];
        float sbuf[8][4];                // [nt][rg] current chunk's scores
        #pragma unroll
        for (int rg = 0; rg < 4; ++rg) minv[rg] = 3.0e38f;

        __syncthreads();                  // chunk 0 staged; cnt ready

        for (int kc = 0; kc < NCHUNK; ++kc) {
            if (kc < NCHUNK - 1) STAGE(cbwL, kc + 1);
            const unsigned short* fb = &cbuf[(kc & 1) * CHUNK_USH];

            // score all 8 nt-tiles into sbuf, update running min
            #pragma unroll
            for (int nt = 0; nt < 8; ++nt) {
                f32x4 acc = {0.f, 0.f, 0.f, 0.f};
                const unsigned short* fp8 = fb + (nt * 8) * 512 + l * 8;
                #pragma unroll
                for (int kk = 0; kk < 8; ++kk) {
                    bf16x8 bfr = *(const bf16x8*)(fp8 + kk * 512);
                    acc = __builtin_amdgcn_mfma_f32_16x16x32_bf16(af[kk], bfr, acc, 0, 0, 0);
                }
                float c2 = cn2L[kc * 128 + nt * 16 + li];   // L1-hot
                #pragma unroll
                for (int rg = 0; rg < 4; ++rg) {
                    float v = __builtin_fmaf(-2.f, acc[rg], c2);
                    sbuf[nt][rg] = v;
                    minv[rg] = fminf(minv[rg], v);
                }
            }

            // fresh per-row threshold (cross-lane min incl. current chunk)
            float rowm[4];
            #pragma unroll
            for (int rg = 0; rg < 4; ++rg) {
                float v = minv[rg];
                v = fminf(v, __shfl_xor(v, 1));
                v = fminf(v, __shfl_xor(v, 2));
                v = fminf(v, __shfl_xor(v, 4));
                v = fminf(v, __shfl_xor(v, 8));
                minv[rg] = v;
                rowm[rg] = v + MARGIN;
            }

            // collect candidates from this chunk
            #pragma unroll
            for (int nt = 0; nt < 8; ++nt) {
                bool any = false;
                #pragma unroll
                for (int rg = 0; rg < 4; ++rg)
                    any |= (sbuf[nt][rg] < rowm[rg]);
                if (__any(any)) {
                    #pragma unroll
                    for (int rg = 0; rg < 4; ++rg)
                        if (sbuf[nt][rg] < rowm[rg]) {
                            int row = w * 16 + 4 * g + rg;
                            int slot = atomicAdd(&cnt[row], 1);
                            if (slot < CAP)
                                cand[row * CAP + slot] =
                                    (unsigned short)(kc * 128 + nt * 16 + li);
                        }
                }
            }
            __syncthreads();   // chunk kc reads done + chunk kc+1 staged
        }

        // issue next level's chunk 0 now — hides under refine + epilogue
        if (lv < 3) STAGE(cbwL + LVL_USH, 0);

        // ---- winner selection: cnt==1 exact; cnt>1 coalesced fp64 rescore;
        //      cnt==0 or >CAP full scan ----
        {
            const int gg = l >> 4;       // candidate slot within quad
            const int q4 = l & 15;       // dim-group: dims q4*4 + j*64
            for (int rr = 0; rr < 16; ++rr) {
                int row = w * 16 + rr;   // this wave's own rows
                int k = cnt[row];
                if (k == 1) {
                    if (l == 0) winid[row] = (int)cand[row * CAP];
                    continue;
                }
                bool list = (k >= 1 && k <= CAP);
                int total = list ? k : KCODES;
                int grow = rows0 + row;
                const float* rrow = rsrc + (size_t)grow * DIM;
                float4 rv[4];
                #pragma unroll
                for (int j = 0; j < 4; ++j)
                    rv[j] = *(const float4*)(rrow + q4 * 4 + j * 64);
                double bestS = 1.0e300; int bestI = 0x7fffffff;
                for (int base = 0; base < total; base += 4) {
                    int slot = base + gg;
                    bool valid = slot < total;
                    int code = valid ? (list ? (int)cand[row * CAP + slot] : slot) : 0;
                    const float* crow = cbf + (size_t)code * DIM;
                    double acc = 0.0;
                    #pragma unroll
                    for (int j = 0; j < 4; ++j) {
                        float4 cv = *(const float4*)(crow + q4 * 4 + j * 64);
                        acc = fma((double)cv.x, (double)rv[j].x, acc);
                        acc = fma((double)cv.y, (double)rv[j].y, acc);
                        acc = fma((double)cv.z, (double)rv[j].z, acc);
                        acc = fma((double)cv.w, (double)rv[j].w, acc);
                    }
                    #pragma unroll
                    for (int m = 1; m <= 8; m <<= 1) acc += __shfl_xor(acc, m);
                    double s = valid ? (cn2dL[code] - 2.0 * acc) : 1.0e300;
                    #pragma unroll
                    for (int gq = 0; gq < 4; ++gq) {
                        double sg = __shfl(s, gq * 16);
                        int cg = __shfl(code, gq * 16);
                        if ((base + gq) < total &&
                            (sg < bestS || (sg == bestS && cg < bestI))) {
                            bestS = sg; bestI = cg;
                        }
                    }
                }
                if (l == 0) winid[row] = bestI;
            }
        }
        __syncthreads();

        // ---- epilogue: write winner ints; r' = r - q (lv < 3) ----
        if (tid < BM)
            wid_out[(size_t)(rows0 + tid) * LEVELS + lv] = winid[tid];
        if (rnext) {
            #pragma unroll
            for (int it = 0; it < 16; ++it) {
                int rowloc = it * 16 + w;
                int grow = rows0 + rowloc;
                int d0 = l * 4;
                int code = winid[rowloc];
                float4 q = *(const float4*)(cbf + (size_t)code * DIM + d0);
                float4 r = *(const float4*)(rsrc + (size_t)grow * DIM + d0);
                float4 rn;
                rn.x = r.x - q.x; rn.y = r.y - q.y;
                rn.z = r.z - q.z; rn.w = r.w - q.w;
                *(float4*)(rnext + (size_t)grow * DIM + d0) = rn;
            }
        }
        // r' visible to this block's next-level reads; winid/cand safe to reuse
        __threadfence_block();
        __syncthreads();
    }
}

// ---- k_final: fp32 chain from data + codes -> zq[0..3], ids, loss partials ----
__global__ __launch_bounds__(256) void k_final(
    const float* __restrict__ data,
    const float* __restrict__ cbf0,        // [4][1024][256]
    int* wid,                              // [N][4] ints; overwritten w/ floats
    float* __restrict__ zq,                // [4][N][256]
    double* __restrict__ blockpart)        // [2048]
{
    __shared__ float wl[4];
    const int tid = threadIdx.x;
    const int w = tid >> 6, l = tid & 63;
    const int rows0 = blockIdx.x * 32;
    float lacc = 0.f;
    #pragma unroll
    for (int i = 0; i < 8; ++i) {
        int grow = rows0 + i * 4 + w;
        int4 c4 = *(const int4*)(wid + (size_t)grow * LEVELS);  // all lanes
        int d0 = l * 4;
        float4 r = *(const float4*)(data + (size_t)grow * DIM + d0);
        float4 z = {0.f, 0.f, 0.f, 0.f};
        int codes[4] = {c4.x, c4.y, c4.z, c4.w};
        #pragma unroll
        for (int lv = 0; lv < LEVELS; ++lv) {
            const float* crow = cbf0 + ((size_t)lv * KCODES + codes[lv]) * DIM;
            float4 q = *(const float4*)(crow + d0);
            float dx = q.x - r.x, dy = q.y - r.y, dz = q.z - r.z, dw = q.w - r.w;
            z.x += (r.x + dx); z.y += (r.y + dy);
            z.z += (r.z + dz); z.w += (r.w + dw);
            *(float4*)(zq + (size_t)lv * CH + (size_t)grow * DIM + d0) = z;
            lacc += dx * dx + dy * dy + dz * dz + dw * dw;
            r.x = -dx; r.y = -dy; r.z = -dz; r.w = -dw;   // r' = r - q exactly
        }
        if (l == 0) {     // ids as floats, over the ints (read-before-write)
            float4 f; f.x = (float)codes[0]; f.y = (float)codes[1];
            f.z = (float)codes[2]; f.w = (float)codes[3];
            *(float4*)((float*)wid + (size_t)grow * LEVELS) = f;
        }
    }
    #pragma unroll
    for (int m = 32; m; m >>= 1) lacc += __shfl_xor(lacc, m);
    if (l == 0) wl[w] = lacc;
    __syncthreads();
    if (tid == 0)
        blockpart[blockIdx.x] =
            (double)wl[0] + (double)wl[1] + (double)wl[2] + (double)wl[3];
}

// ---- k_loss: deterministic fixed-order reduction of block partials ----
__global__ __launch_bounds__(256) void k_loss(const double* __restrict__ part,
                                              float* __restrict__ loss) {
    __shared__ double sd[256];
    int tid = threadIdx.x;
    double a = 0.0;
    #pragma unroll
    for (int i = 0; i < 8; ++i) a += part[i * 256 + tid];   // 2048 entries
    sd[tid] = a; __syncthreads();
    for (int s = 128; s > 0; s >>= 1) {
        if (tid < s) sd[tid] += sd[tid + s];
        __syncthreads();
    }
    if (tid == 0) *loss = (float)(sd[0] * (1.25 / 16777216.0));
}

extern "C" void kernel_launch(void* const* d_in, const int* in_sizes, int n_in,
                              void* d_out, int out_size, void* d_ws, size_t ws_size,
                              hipStream_t stream) {
    const float* data = (const float*)d_in[0];
    const float* cb   = (const float*)d_in[1];
    float* out  = (float*)d_out;
    float* zq   = out;
    int*   wid  = (int*)(out + IDS_OFF);   // ids region doubles as int winners
    float* loss = out + IDS_OFF + NROWS * LEVELS;
    char* ws = (char*)d_ws;
    unsigned short* cbw = (unsigned short*)ws;                 // 2 MB frag-tiled bf16
    float*  cn2w  = (float*)(ws + (size_t)LEVELS * LVL_USH * 2);           // 16 KB
    double* cn2d  = (double*)(ws + (size_t)LEVELS * LVL_USH * 2 + 16384);  // 32 KB
    double* bpart = (double*)(ws + (size_t)LEVELS * LVL_USH * 2 + 16384 + 32768); // 16 KB
    float* rscr = zq + (size_t)3 * CH;   // zq_stack[3] slot = residual scratch

    k_prep<<<LEVELS * KCODES, 64, 0, stream>>>(cb, cbw, cn2w, cn2d);
    k_score4<<<NROWS / BM, 1024, 0, stream>>>(data, cb, cbw, cn2w, cn2d,
                                              wid, rscr);
    k_final<<<NROWS / 32, 256, 0, stream>>>(data, cb, wid, zq, bpart);
    k_loss<<<1, 256, 0, stream>>>(bpart, loss);
}

// Round 20
// 470.187 us; speedup vs baseline: 1.1379x; 1.1379x over previous
//
#include <hip/hip_runtime.h>
#include <hip/hip_bf16.h>

// RQ-VAE residual quantization, MI355X gfx950 — phase-split pipeline (r17
// structure + streaming-tail polish; r19 compile fix: nontemporal stores
// go through ext_vector f32x4, not HIP_vector_type float4).
// data [65536][256] f32, codebooks [4][1024][256] f32.
// out = [zq_stack 4*65536*256][semantic_ids 65536*4 (as float)][loss 1], all f32.
//
// k_score (unchanged from r17, the measured best): BM=256 rows, 1024
// threads = 16 waves x 16 rows, ONE block per CU (grid 256), 128-code
// chunks in a 2x64KB LDS double buffer -> 8 barriers/level. Single-pass
// scores, candidates vs post-chunk running-min + MARGIN; true argmin
// ALWAYS collected (bf16 error bound 2*3.45 < 8) so cnt==1 rows take their
// sole candidate (exact); cnt>1 -> wave-cooperative coalesced fp64 rescore
// (exact, lowest-index tie-break); cnt==0 or >CAP -> full scan. Fused
// epilogue writes winner ints + r' = r - q.
// k_final: nontemporal stores for the 257 MB of write-once zq/ids (bypass
// L2, keep it for data/codebook reads). k_prep: 256-thread blocks.
// Residual scratch = zq_stack[3] slot of d_out (read-before-write).
// NOTE: WRITE_SIZE ~65 MB in k_score lv<3 is the legit r' write, not spills.

#define NROWS   65536
#define DIM     256
#define KCODES  1024
#define LEVELS  4
#define CH      (NROWS * DIM)
#define IDS_OFF (LEVELS * CH)

#define BM      256
#define NCHUNK  8
#define CAP     32
#define MARGIN  8.0f
#define CHUNK_USH 32768          // 128 codes * 256 bf16 = 64 KB
#define LVL_USH 262144           // 1024 * 256

typedef __attribute__((ext_vector_type(8))) short bf16x8;
typedef __attribute__((ext_vector_type(4))) float f32x4;
typedef const __attribute__((address_space(1))) void* gp_t;
typedef __attribute__((address_space(3))) void* lp_t;

__device__ __forceinline__ unsigned short f2bf(float x) {
    __hip_bfloat16 h = __float2bfloat16(x);
    unsigned short r; __builtin_memcpy(&r, &h, 2); return r;
}
__device__ __forceinline__ float bf2f(unsigned short u) {
    __hip_bfloat16 h; __builtin_memcpy(&h, &u, 2); return __bfloat162float(h);
}
__device__ __forceinline__ void nt_store4(float* p, float x, float y,
                                          float z, float w) {
    f32x4 v; v[0] = x; v[1] = y; v[2] = z; v[3] = w;
    __builtin_nontemporal_store(v, (f32x4*)p);
}

// ---- k_prep: frag-tiled bf16 codebook + fp32 sum(c_bf16^2) + fp64 sum(c^2) ----
// 256 threads = 4 code-rows per block. Layout (ushort idx):
// ((((L*16+chunk64)*4+nt)*8+kk)*64 + (g*16+li))*8 + h — contiguous in code
// order: codes t*128..t*128+127 live at cbwL + t*CHUNK_USH.
__global__ __launch_bounds__(256) void k_prep(const float* __restrict__ cb,
                                              unsigned short* __restrict__ cbw,
                                              float* __restrict__ cn2w,
                                              double* __restrict__ cn2d) {
    int cr = blockIdx.x * 4 + (threadIdx.x >> 6);  // level*1024 + code
    int L = cr >> 10, c = cr & 1023;
    int l = threadIdx.x & 63;            // handles floats l*4..l*4+3
    float4 v = *(const float4*)(cb + (size_t)cr * DIM + l * 4);
    ushort4 st;
    st.x = f2bf(v.x); st.y = f2bf(v.y); st.z = f2bf(v.z); st.w = f2bf(v.w);
    int b = l * 8;
    int kk = b >> 6, g = (b >> 4) & 3, h = (b & 15) >> 1;
    int idx = ((((L * 16 + (c >> 6)) * 4 + ((c >> 4) & 3)) * 8 + kk) * 64
               + (g * 16 + (c & 15))) * 8 + h;
    *(ushort4*)(cbw + idx) = st;
    float f0 = bf2f(st.x), f1 = bf2f(st.y), f2 = bf2f(st.z), f3 = bf2f(st.w);
    float sq = f0 * f0 + f1 * f1 + f2 * f2 + f3 * f3;
    double dq = (double)v.x * v.x + (double)v.y * v.y
              + (double)v.z * v.z + (double)v.w * v.w;
    #pragma unroll
    for (int m = 32; m; m >>= 1) {
        sq += __shfl_xor(sq, m);
        dq += __shfl_xor(dq, m);
    }
    if (l == 0) { cn2w[cr] = sq; cn2d[cr] = dq; }
}

// ---- k_score: 16-wave single-pass scores + cnt==1 skip + coalesced refine +
//      fused residual epilogue (r17, unchanged) ----
__global__ __launch_bounds__(1024) void k_score(
    const float* rsrc,                        // residual (or data) [N][256]
    const float* __restrict__ cbf,            // f32 codebook, this level
    const unsigned short* __restrict__ cbwL,  // frag-tiled bf16 codebook
    const float* __restrict__ cn2L,           // [1024] fp32 sum of bf16-c^2
    const double* __restrict__ cn2dL,         // [1024] fp64 sum of c^2
    int* __restrict__ wid_out,                // [N][4] ints (ids slot)
    float* rnext,                             // r' = r - q, or null (lv 3)
    int level)
{
    __shared__ unsigned short cbuf[2 * CHUNK_USH];   // 128 KB double buffer
    __shared__ unsigned short cand[BM * CAP];        // 16 KB
    __shared__ int cnt[BM];
    __shared__ int winid[BM];

    const int tid = threadIdx.x;
    const int w = tid >> 6, l = tid & 63;
    const int g = l >> 4, li = l & 15;
    const int rows0 = blockIdx.x * BM;

    // stage 128-code chunk T into buffer T&1 (linear DMA: 4x16B per thread)
    #define STAGE(T) do {                                                      \
        const unsigned short* _g = cbwL + (T) * CHUNK_USH;                     \
        unsigned short* _d = &cbuf[((T) & 1) * CHUNK_USH];                     \
        _Pragma("unroll")                                                      \
        for (int _r = 0; _r < 4; ++_r)                                         \
            __builtin_amdgcn_global_load_lds((gp_t)(_g + _r * 8192 + tid * 8), \
                                             (lp_t)(_d + _r * 8192 + tid * 8), \
                                             16, 0, 0);                        \
    } while (0)

    STAGE(0);
    if (tid < BM) cnt[tid] = 0;

    // A-fragments: 16 rows per wave in bf16 registers (reused all chunks)
    bf16x8 af[8];
    {
        int row = rows0 + w * 16 + li;
        const float* rp = rsrc + (size_t)row * DIM;
        #pragma unroll
        for (int kk = 0; kk < 8; ++kk) {
            int d0 = kk * 32 + 8 * g;
            float4 v0 = *(const float4*)(rp + d0);
            float4 v1 = *(const float4*)(rp + d0 + 4);
            bf16x8 t;
            t[0] = (short)f2bf(v0.x); t[1] = (short)f2bf(v0.y);
            t[2] = (short)f2bf(v0.z); t[3] = (short)f2bf(v0.w);
            t[4] = (short)f2bf(v1.x); t[5] = (short)f2bf(v1.y);
            t[6] = (short)f2bf(v1.z); t[7] = (short)f2bf(v1.w);
            af[kk] = t;
        }
    }

    // per-lane running min only (lanes see disjoint codes)
    float minv[4];
    float sbuf[8][4];                    // [nt][rg] current chunk's scores
    #pragma unroll
    for (int rg = 0; rg < 4; ++rg) minv[rg] = 3.0e38f;

    __syncthreads();                      // chunk 0 staged; cnt ready

    for (int kc = 0; kc < NCHUNK; ++kc) {
        if (kc < NCHUNK - 1) STAGE(kc + 1);     // next chunk under compute
        const unsigned short* fb = &cbuf[(kc & 1) * CHUNK_USH];

        // score all 8 nt-tiles into sbuf, update running min
        #pragma unroll
        for (int nt = 0; nt < 8; ++nt) {
            f32x4 acc = {0.f, 0.f, 0.f, 0.f};
            const unsigned short* fp8 = fb + (nt * 8) * 512 + l * 8;
            #pragma unroll
            for (int kk = 0; kk < 8; ++kk) {
                bf16x8 bfr = *(const bf16x8*)(fp8 + kk * 512);
                acc = __builtin_amdgcn_mfma_f32_16x16x32_bf16(af[kk], bfr, acc, 0, 0, 0);
            }
            float c2 = cn2L[kc * 128 + nt * 16 + li];   // L1-hot
            #pragma unroll
            for (int rg = 0; rg < 4; ++rg) {
                float v = __builtin_fmaf(-2.f, acc[rg], c2);
                sbuf[nt][rg] = v;
                minv[rg] = fminf(minv[rg], v);
            }
        }

        // fresh per-row threshold (cross-lane min incl. current chunk)
        float rowm[4];
        #pragma unroll
        for (int rg = 0; rg < 4; ++rg) {
            float v = minv[rg];
            v = fminf(v, __shfl_xor(v, 1));
            v = fminf(v, __shfl_xor(v, 2));
            v = fminf(v, __shfl_xor(v, 4));
            v = fminf(v, __shfl_xor(v, 8));
            minv[rg] = v;
            rowm[rg] = v + MARGIN;
        }

        // collect candidates from this chunk with the post-chunk threshold
        #pragma unroll
        for (int nt = 0; nt < 8; ++nt) {
            bool any = false;
            #pragma unroll
            for (int rg = 0; rg < 4; ++rg)
                any |= (sbuf[nt][rg] < rowm[rg]);
            if (__any(any)) {
                #pragma unroll
                for (int rg = 0; rg < 4; ++rg)
                    if (sbuf[nt][rg] < rowm[rg]) {
                        int row = w * 16 + 4 * g + rg;
                        int slot = atomicAdd(&cnt[row], 1);
                        if (slot < CAP)
                            cand[row * CAP + slot] =
                                (unsigned short)(kc * 128 + nt * 16 + li);
                    }
            }
        }
        __syncthreads();   // chunk kc reads done + chunk kc+1 staged
    }

    // ---- winner selection:
    //      cnt==1 -> the sole candidate IS the exact argmin (true winner is
    //      always collected); cnt>1 -> wave-cooperative coalesced fp64
    //      rescore; cnt==0 or cnt>CAP -> sound full scan ----
    {
        const int gg = l >> 4;           // candidate slot within quad
        const int q4 = l & 15;           // dim-group: dims q4*4 + j*64
        for (int rr = 0; rr < 16; ++rr) {
            int row = w * 16 + rr;       // this wave's own rows
            int k = cnt[row];
            if (k == 1) {
                if (l == 0) winid[row] = (int)cand[row * CAP];
                continue;
            }
            bool list = (k >= 1 && k <= CAP);
            int total = list ? k : KCODES;
            int grow = rows0 + row;
            const float* rrow = rsrc + (size_t)grow * DIM;
            float4 rv[4];
            #pragma unroll
            for (int j = 0; j < 4; ++j)
                rv[j] = *(const float4*)(rrow + q4 * 4 + j * 64);
            double bestS = 1.0e300; int bestI = 0x7fffffff;
            for (int base = 0; base < total; base += 4) {
                int slot = base + gg;
                bool valid = slot < total;
                int code = valid ? (list ? (int)cand[row * CAP + slot] : slot) : 0;
                const float* crow = cbf + (size_t)code * DIM;
                double acc = 0.0;
                #pragma unroll
                for (int j = 0; j < 4; ++j) {
                    float4 cv = *(const float4*)(crow + q4 * 4 + j * 64);
                    acc = fma((double)cv.x, (double)rv[j].x, acc);
                    acc = fma((double)cv.y, (double)rv[j].y, acc);
                    acc = fma((double)cv.z, (double)rv[j].z, acc);
                    acc = fma((double)cv.w, (double)rv[j].w, acc);
                }
                #pragma unroll
                for (int m = 1; m <= 8; m <<= 1) acc += __shfl_xor(acc, m);
                double s = valid ? (cn2dL[code] - 2.0 * acc) : 1.0e300;
                #pragma unroll
                for (int gq = 0; gq < 4; ++gq) {
                    double sg = __shfl(s, gq * 16);
                    int cg = __shfl(code, gq * 16);
                    if ((base + gq) < total &&
                        (sg < bestS || (sg == bestS && cg < bestI))) {
                        bestS = sg; bestI = cg;
                    }
                }
            }
            if (l == 0) winid[row] = bestI;
        }
    }
    __syncthreads();

    // ---- epilogue: write winner ints; fused r' = r - q (lv < 3) ----
    if (tid < BM)
        wid_out[(size_t)(rows0 + tid) * LEVELS + level] = winid[tid];
    if (rnext) {
        #pragma unroll
        for (int it = 0; it < 16; ++it) {
            int rowloc = it * 16 + w;
            int grow = rows0 + rowloc;
            int d0 = l * 4;
            int code = winid[rowloc];
            float4 q = *(const float4*)(cbf + (size_t)code * DIM + d0);
            float4 r = *(const float4*)(rsrc + (size_t)grow * DIM + d0);
            float4 rn;
            rn.x = r.x - q.x; rn.y = r.y - q.y;
            rn.z = r.z - q.z; rn.w = r.w - q.w;
            *(float4*)(rnext + (size_t)grow * DIM + d0) = rn;
        }
    }
}

// ---- k_final: fp32 chain from data + codes -> zq[0..3], ids, loss partials.
//      zq/ids stores are nontemporal (write-once, bypass L2). ----
__global__ __launch_bounds__(256) void k_final(
    const float* __restrict__ data,
    const float* __restrict__ cbf0,        // [4][1024][256]
    int* wid,                              // [N][4] ints; overwritten w/ floats
    float* __restrict__ zq,                // [4][N][256]
    double* __restrict__ blockpart)        // [2048]
{
    __shared__ float wl[4];
    const int tid = threadIdx.x;
    const int w = tid >> 6, l = tid & 63;
    const int rows0 = blockIdx.x * 32;
    float lacc = 0.f;
    #pragma unroll
    for (int i = 0; i < 8; ++i) {
        int grow = rows0 + i * 4 + w;
        int4 c4 = *(const int4*)(wid + (size_t)grow * LEVELS);  // all lanes
        int d0 = l * 4;
        float4 r = *(const float4*)(data + (size_t)grow * DIM + d0);
        float4 z = {0.f, 0.f, 0.f, 0.f};
        int codes[4] = {c4.x, c4.y, c4.z, c4.w};
        #pragma unroll
        for (int lv = 0; lv < LEVELS; ++lv) {
            const float* crow = cbf0 + ((size_t)lv * KCODES + codes[lv]) * DIM;
            float4 q = *(const float4*)(crow + d0);
            float dx = q.x - r.x, dy = q.y - r.y, dz = q.z - r.z, dw = q.w - r.w;
            z.x += (r.x + dx); z.y += (r.y + dy);
            z.z += (r.z + dz); z.w += (r.w + dw);
            nt_store4(zq + (size_t)lv * CH + (size_t)grow * DIM + d0,
                      z.x, z.y, z.z, z.w);
            lacc += dx * dx + dy * dy + dz * dz + dw * dw;
            r.x = -dx; r.y = -dy; r.z = -dz; r.w = -dw;   // r' = r - q exactly
        }
        if (l == 0) {     // ids as floats, over the ints (read-before-write)
            nt_store4((float*)wid + (size_t)grow * LEVELS,
                      (float)codes[0], (float)codes[1],
                      (float)codes[2], (float)codes[3]);
        }
    }
    #pragma unroll
    for (int m = 32; m; m >>= 1) lacc += __shfl_xor(lacc, m);
    if (l == 0) wl[w] = lacc;
    __syncthreads();
    if (tid == 0)
        blockpart[blockIdx.x] =
            (double)wl[0] + (double)wl[1] + (double)wl[2] + (double)wl[3];
}

// ---- k_loss: deterministic fixed-order reduction of block partials ----
__global__ __launch_bounds__(256) void k_loss(const double* __restrict__ part,
                                              float* __restrict__ loss) {
    __shared__ double sd[256];
    int tid = threadIdx.x;
    double a = 0.0;
    #pragma unroll
    for (int i = 0; i < 8; ++i) a += part[i * 256 + tid];   // 2048 entries
    sd[tid] = a; __syncthreads();
    for (int s = 128; s > 0; s >>= 1) {
        if (tid < s) sd[tid] += sd[tid + s];
        __syncthreads();
    }
    if (tid == 0) *loss = (float)(sd[0] * (1.25 / 16777216.0));
}

extern "C" void kernel_launch(void* const* d_in, const int* in_sizes, int n_in,
                              void* d_out, int out_size, void* d_ws, size_t ws_size,
                              hipStream_t stream) {
    const float* data = (const float*)d_in[0];
    const float* cb   = (const float*)d_in[1];
    float* out  = (float*)d_out;
    float* zq   = out;
    int*   wid  = (int*)(out + IDS_OFF);   // ids region doubles as int winners
    float* loss = out + IDS_OFF + NROWS * LEVELS;
    char* ws = (char*)d_ws;
    unsigned short* cbw = (unsigned short*)ws;                 // 2 MB frag-tiled bf16
    float*  cn2w  = (float*)(ws + (size_t)LEVELS * LVL_USH * 2);           // 16 KB
    double* cn2d  = (double*)(ws + (size_t)LEVELS * LVL_USH * 2 + 16384);  // 32 KB
    double* bpart = (double*)(ws + (size_t)LEVELS * LVL_USH * 2 + 16384 + 32768); // 16 KB
    float* rscr = zq + (size_t)3 * CH;   // zq_stack[3] slot = residual scratch

    k_prep<<<LEVELS * KCODES / 4, 256, 0, stream>>>(cb, cbw, cn2w, cn2d);
    for (int lv = 0; lv < LEVELS; ++lv) {
        const float* rsrc = (lv == 0) ? data : rscr;
        float* rnext = (lv < 3) ? rscr : nullptr;
        k_score<<<NROWS / BM, 1024, 0, stream>>>(
            rsrc, cb + (size_t)lv * KCODES * DIM, cbw + (size_t)lv * LVL_USH,
            cn2w + (size_t)lv * KCODES, cn2d + (size_t)lv * KCODES,
            wid, rnext, lv);
    }
    k_final<<<NROWS / 32, 256, 0, stream>>>(data, cb, wid, zq, bpart);
    k_loss<<<1, 256, 0, stream>>>(bpart, loss);
}